// Round 12
// baseline (461.149 us; speedup 1.0000x reference)
//
#include <hip/hip_runtime.h>
#include <hip/hip_bf16.h>
#include <stdint.h>

// ParaGraph: 2 node types (net/cell, N=100000), 3 relations (E=600000 each), D=128.
// I/O FP32. All intermediates bf16. W pre-converted bf16. 6 dispatches:
// prep | logbh | bscan | bscatter | sortgemm | tail.
// sortgemm's sort path precomputes normalized softmax edge weights (walpha).
// tail_k: node-local pipeline; net blocks run BOTH gathers (r0,r2) in one
// interleaved register loop (gat_dual) -- 8 h-row loads in flight, half the
// serial latency rounds. gat2's sum is added after F^2 (data-independent).
#define NN 100000
#define NE 600000
#define SP 136        // LDS row stride (ushorts): 128 + 8 pad
#define NB 782        // ceil(NN/128) dst buckets of 128 nodes
#define BCAP 1600     // LDS rec capacity per bucket (mean 767, sd ~28)
#define CHUNK 4096    // edges per partition block
#define NCH 147       // ceil(NE/CHUNK)
#define GB 1563       // ceil(NN/64) GEMM row-blocks
#define AB 6250       // NN/16 node-tile blocks (exact)

typedef unsigned short u16;
typedef unsigned int u32;
typedef __attribute__((ext_vector_type(8))) short short8;
typedef __attribute__((ext_vector_type(8))) __bf16 bf16x8;
typedef __attribute__((ext_vector_type(4))) float floatx4;

__device__ __forceinline__ float b2f(u16 u) {
  union { float f; u32 i; } c; c.i = ((u32)u) << 16; return c.f;
}
__device__ __forceinline__ u16 f2b(float f) {
  union { float f; u32 i; } c; c.f = f;
  u32 r = c.i + 0x7FFFu + ((c.i >> 16) & 1u);  // RNE
  return (u16)(r >> 16);
}

// ================= device bodies =================

// one W-tile pass (64-row GEMM): stage W -> sync -> MFMA -> store C
__device__ __forceinline__ void gemm_w(const u16* __restrict__ W, int ldw, u16* __restrict__ C,
                                       u16* lds, int tid, int row0, const bf16x8* a,
                                       int m16, int quad, int wv) {
#pragma unroll
  for (int it = 0; it < 8; ++it) {
    int idx = it * 256 + tid;
    int r = idx >> 4, c = (idx & 15) << 3;
    *(short8*)(&lds[r * SP + c]) = *(const short8*)(W + (size_t)r * ldw + c);
  }
  __syncthreads();
  const u16* brow = &lds[m16 * SP + quad * 8];
  floatx4 acc[8];
#pragma unroll
  for (int c = 0; c < 8; ++c) acc[c] = floatx4{0.f, 0.f, 0.f, 0.f};
#pragma unroll
  for (int kk = 0; kk < 4; ++kk) {
#pragma unroll
    for (int c = 0; c < 8; ++c) {
      bf16x8 bfr = *(const bf16x8*)(brow + c * 16 * SP + kk * 32);
      acc[c] = __builtin_amdgcn_mfma_f32_16x16x32_bf16(a[kk], bfr, acc[c], 0, 0, 0);
    }
  }
#pragma unroll
  for (int c = 0; c < 8; ++c) {
    int col = c * 16 + m16;
#pragma unroll
    for (int r = 0; r < 4; ++r) {
      int grow = row0 + wv * 16 + quad * 4 + r;
      if (grow < NN) C[(size_t)grow * 128 + col] = f2b(acc[c][r]);
    }
  }
}

// stage W2 (Wl cols 128..255, ldw 256) into LDS -- plain 16B copies (256 threads)
__device__ __forceinline__ void stageW2(const u16* __restrict__ W2, u16* Wlds, int tid) {
#pragma unroll
  for (int it = 0; it < 8; ++it) {
    int idx = it * 256 + tid;
    int r = idx >> 4, c = (idx & 15) << 3;
    *(short8*)(&Wlds[r * SP + c]) = *(const short8*)(W2 + (size_t)r * 256 + c);
  }
}

// single gather (cell path): group g (16 lanes) accumulates node n's pre-normalized
// edges into Alds row g. INIT=1: start from current Alds row (same-thread slot).
template<int INIT>
__device__ __forceinline__ void gat_phase(int nb, int tid, const u16* __restrict__ h,
                                          const u32* __restrict__ srecs,
                                          const float* __restrict__ walpha,
                                          const int* __restrict__ rp, u16* Alds) {
  int sub = tid & 15, g = tid >> 4;
  int n = nb * 16 + g;                    // NN = 6250*16, no tail
  int start = rp[n], end = rp[n + 1];
  float row[8];
  if (INIT) {
    short8 pv = *(const short8*)(&Alds[g * SP + sub * 8]);
#pragma unroll
    for (int t = 0; t < 8; ++t) row[t] = b2f((u16)pv[t]);
  } else {
#pragma unroll
    for (int t = 0; t < 8; ++t) row[t] = 0.f;
  }
  if (start < end) {
    float acc[8];
#pragma unroll
    for (int t = 0; t < 8; ++t) acc[t] = 0.f;
    const u16* hsub = h + sub * 8;
    int e = start;
    for (; e < end; e += 4) {
      int m = end - e; if (m > 4) m = 4;
      int s[4]; float x[4]; short8 hv[4];
#pragma unroll
      for (int j = 0; j < 4; ++j) {
        if (j < m) { s[j] = (int)srecs[e + j]; x[j] = walpha[e + j]; }
      }
#pragma unroll
      for (int j = 0; j < 4; ++j) {
        if (j < m) hv[j] = *(const short8*)(hsub + (size_t)s[j] * 128);
      }
#pragma unroll
      for (int j = 0; j < 4; ++j) {
        if (j < m) {
          float xx = x[j];
#pragma unroll
          for (int t = 0; t < 8; ++t) acc[t] += xx * b2f((u16)hv[j][t]);
        }
      }
    }
#pragma unroll
    for (int t = 0; t < 8; ++t) row[t] += acc[t];
  }
  short8 rb;
#pragma unroll
  for (int t = 0; t < 8; ++t) rb[t] = (short)f2b(row[t]);
  *(short8*)(&Alds[g * SP + sub * 8]) = rb;
}

// dual gather (net path): both relations' edges accumulated in one interleaved loop.
// Each round issues up to 4+4 independent h-row loads before any fma waits.
__device__ __forceinline__ void gat_dual(int n, int sub,
                                         const u16* __restrict__ hA, const u32* __restrict__ srA,
                                         const float* __restrict__ waA, const int* __restrict__ rpA,
                                         const u16* __restrict__ hB, const u32* __restrict__ srB,
                                         const float* __restrict__ waB, const int* __restrict__ rpB,
                                         float* accA, float* accB) {
  int eA = rpA[n], endA = rpA[n + 1];
  int eB = rpB[n], endB = rpB[n + 1];
#pragma unroll
  for (int t = 0; t < 8; ++t) { accA[t] = 0.f; accB[t] = 0.f; }
  const u16* hsubA = hA + sub * 8;
  const u16* hsubB = hB + sub * 8;
  while (eA < endA || eB < endB) {
    int mA = endA - eA; if (mA > 4) mA = 4;
    int mB = endB - eB; if (mB > 4) mB = 4;
    int sA[4], sB[4]; float xA[4], xB[4];
#pragma unroll
    for (int j = 0; j < 4; ++j) {
      if (j < mA) { sA[j] = (int)srA[eA + j]; xA[j] = waA[eA + j]; }
    }
#pragma unroll
    for (int j = 0; j < 4; ++j) {
      if (j < mB) { sB[j] = (int)srB[eB + j]; xB[j] = waB[eB + j]; }
    }
    short8 hvA[4], hvB[4];
#pragma unroll
    for (int j = 0; j < 4; ++j) {
      if (j < mA) hvA[j] = *(const short8*)(hsubA + (size_t)sA[j] * 128);
    }
#pragma unroll
    for (int j = 0; j < 4; ++j) {
      if (j < mB) hvB[j] = *(const short8*)(hsubB + (size_t)sB[j] * 128);
    }
#pragma unroll
    for (int j = 0; j < 4; ++j) {
      if (j < mA) {
        float x = xA[j];
#pragma unroll
        for (int t = 0; t < 8; ++t) accA[t] += x * b2f((u16)hvA[j][t]);
      }
    }
#pragma unroll
    for (int j = 0; j < 4; ++j) {
      if (j < mB) {
        float x = xB[j];
#pragma unroll
        for (int t = 0; t < 8; ++t) accB[t] += x * b2f((u16)hvB[j][t]);
      }
    }
    if (mA > 0) eA += mA;
    if (mB > 0) eB += mB;
  }
}

// F phase (256 threads, 16 rows): tile = relu(P + Alds @ W2.T + c).
// TO_GLOBAL: fp32 out; else bf16 -> Alds.
template<int TO_GLOBAL>
__device__ __forceinline__ void F_phase(int nb, int tid, const u16* __restrict__ P,
                                        const float* __restrict__ cvec,
                                        const u16* Wlds, u16* Alds, void* __restrict__ out) {
  const int lane = tid & 63, wv = tid >> 6;
  const int m16 = lane & 15, quad = lane >> 4;
  const u16* arow = &Alds[m16 * SP + quad * 8];
  bf16x8 a[4];
#pragma unroll
  for (int kk = 0; kk < 4; ++kk) a[kk] = *(const bf16x8*)(arow + kk * 32);
  if (!TO_GLOBAL) __syncthreads();      // all A reads landed before overwrite
  const u16* brow = &Wlds[m16 * SP + quad * 8];
  floatx4 acc2[2];
#pragma unroll
  for (int cc = 0; cc < 2; ++cc) acc2[cc] = floatx4{0.f, 0.f, 0.f, 0.f};
#pragma unroll
  for (int kk = 0; kk < 4; ++kk) {
#pragma unroll
    for (int cc = 0; cc < 2; ++cc) {
      int ct = wv * 2 + cc;
      bf16x8 bfr = *(const bf16x8*)(brow + ct * 16 * SP + kk * 32);
      acc2[cc] = __builtin_amdgcn_mfma_f32_16x16x32_bf16(a[kk], bfr, acc2[cc], 0, 0, 0);
    }
  }
#pragma unroll
  for (int cc = 0; cc < 2; ++cc) {
    int ct = wv * 2 + cc;
    int col = ct * 16 + m16;
    float cv = cvec[col];
#pragma unroll
    for (int r = 0; r < 4; ++r) {
      int nrow = quad * 4 + r;
      int node = nb * 16 + nrow;
      float v = acc2[cc][r] + b2f(P[(size_t)node * 128 + col]) + cv;
      v = fmaxf(v, 0.f);
      if (TO_GLOBAL) ((float*)out)[(size_t)node * 128 + col] = v;
      else           Alds[nrow * SP + col] = f2b(v);
    }
  }
  if (!TO_GLOBAL) __syncthreads();      // tile complete before next phase reads
}

// ================= kernels =================

// prep: proj (12500) | conv (128) | vec (7) | zero bcnt (3)
__global__ __launch_bounds__(256) void prep_k(const float* __restrict__ x_net, const float* __restrict__ x_cell,
                                              const float* __restrict__ Wp_net, const float* __restrict__ Wp_cell,
                                              u16* __restrict__ feat_net, u16* __restrict__ feat_cell,
                                              const float* __restrict__ Wl, const float* __restrict__ Wg0,
                                              const float* __restrict__ Wg1, const float* __restrict__ Wg2,
                                              u16* __restrict__ Wl_bf, u16* __restrict__ Wg_bf,
                                              const float* al0, const float* ar0, const float* al1,
                                              const float* ar1, const float* al2, const float* ar2,
                                              const float* bias, float* __restrict__ vecs,
                                              int* __restrict__ bcnt) {
  int bid = blockIdx.x, tid = threadIdx.x;
  if (bid < 2 * AB) {
    int y = bid >= AB;
    int bx = y ? bid - AB : bid;
    const float* x  = y ? x_cell : x_net;
    const float* Wp = y ? Wp_cell : Wp_net;
    u16* feat       = y ? feat_cell : feat_net;
    __shared__ float Ws[128 * 17];
    __shared__ float xs[16][17];
#pragma unroll
    for (int it = 0; it < 8; ++it) {
      int idx = it * 256 + tid;
      int j = idx >> 4, k = idx & 15;
      Ws[j * 17 + k] = Wp[idx];
    }
    int n0 = bx * 16;
    { int nn = tid >> 4, k = tid & 15;
      xs[nn][k] = x[(size_t)(n0 + nn) * 16 + k]; }
    __syncthreads();
    int j = tid & 127, g = tid >> 7;
    float acc[8];
#pragma unroll
    for (int r = 0; r < 8; ++r) acc[r] = 0.f;
#pragma unroll
    for (int k = 0; k < 16; ++k) {
      float w = Ws[j * 17 + k];
#pragma unroll
      for (int r = 0; r < 8; ++r) acc[r] += xs[g * 8 + r][k] * w;
    }
#pragma unroll
    for (int r = 0; r < 8; ++r)
      feat[(size_t)(n0 + g * 8 + r) * 128 + j] = f2b(acc[r]);
  } else if (bid < 2 * AB + 128) {
    int cid = bid - 2 * AB;
    int y = cid >> 5, bx = cid & 31;
    const float* src = (y == 0) ? Wl : (y == 1) ? Wg0 : (y == 2) ? Wg1 : Wg2;
    u16* dst = (y == 0) ? Wl_bf : Wg_bf + (size_t)(y - 1) * 16384;
    int n = (y == 0) ? 32768 : 16384;
    int i = (bx * 256 + tid) * 4;
    if (i >= n) return;
    float4 v = *(const float4*)(src + i);
    ushort4 p; p.x = f2b(v.x); p.y = f2b(v.y); p.z = f2b(v.z); p.w = f2b(v.w);
    *(ushort4*)(dst + i) = p;
  } else if (bid < 2 * AB + 135) {
    int a = bid - (2 * AB + 128);
    if (tid >= 128) return;
    int j = tid;
    float s = 0.f;
    if (a < 6) {
      const float* W = (a < 2) ? Wg0 : (a < 4) ? Wg1 : Wg2;
      const float* v = (a == 0) ? al0 : (a == 1) ? ar0 : (a == 2) ? al1 : (a == 3) ? ar1 : (a == 4) ? al2 : ar2;
      for (int i = 0; i < 128; ++i) s += W[i * 128 + j] * v[i];
    } else {
      for (int i = 0; i < 128; ++i) s += Wl[(size_t)j * 256 + 128 + i] * bias[i];
    }
    vecs[a * 128 + j] = s;
  } else {
    int r = bid - (2 * AB + 135);
    for (int i = tid; i < NB; i += 256) bcnt[(size_t)r * NB + i] = 0;
  }
}

// logbh: logits (782) | bhist (441)
__global__ __launch_bounds__(256) void logbh_k(const u16* __restrict__ feat_net, const u16* __restrict__ feat_cell,
                                               const float* __restrict__ vecs, float* __restrict__ outs,
                                               const int* __restrict__ dst0, const int* __restrict__ dst1,
                                               const int* __restrict__ dst2, int* __restrict__ bcnt) {
  __shared__ int sm[NB];
  int bid = blockIdx.x, tid = threadIdx.x;
  if (bid < 782) {
    float* vs = (float*)sm;
#pragma unroll
    for (int it = 0; it < 3; ++it) vs[it * 256 + tid] = vecs[it * 256 + tid];
    __syncthreads();
    int y = bid >= 391;
    int bx = y ? bid - 391 : bid;
    const u16* f = y ? feat_cell : feat_net;
    int n = bx * 256 + tid;
    if (n >= NN) return;
    const u16* row = f + (size_t)n * 128;
    if (y == 0) {
      float s1 = 0.f, s2 = 0.f, s4 = 0.f, s5 = 0.f;
#pragma unroll
      for (int k = 0; k < 128; k += 8) {
        short8 u = *(const short8*)(row + k);
#pragma unroll
        for (int t = 0; t < 8; ++t) {
          float fv = b2f((u16)u[t]);
          s1 += fv * vs[1 * 128 + k + t]; s2 += fv * vs[2 * 128 + k + t];
          s4 += fv * vs[4 * 128 + k + t]; s5 += fv * vs[5 * 128 + k + t];
        }
      }
      outs[(size_t)1 * NN + n] = s1; outs[(size_t)2 * NN + n] = s2;
      outs[(size_t)4 * NN + n] = s4; outs[(size_t)5 * NN + n] = s5;
    } else {
      float s0 = 0.f, s3 = 0.f;
#pragma unroll
      for (int k = 0; k < 128; k += 8) {
        short8 u = *(const short8*)(row + k);
#pragma unroll
        for (int t = 0; t < 8; ++t) {
          float fv = b2f((u16)u[t]);
          s0 += fv * vs[0 * 128 + k + t]; s3 += fv * vs[3 * 128 + k + t];
        }
      }
      outs[(size_t)0 * NN + n] = s0; outs[(size_t)3 * NN + n] = s3;
    }
  } else {
    int e = bid - 782;
    int r = e / NCH, bx = e % NCH;
    const int* dst = (r == 0) ? dst0 : (r == 1) ? dst1 : dst2;
    for (int i = tid; i < NB; i += 256) sm[i] = 0;
    __syncthreads();
    int e0 = bx * CHUNK;
    int cnt = NE - e0; if (cnt > CHUNK) cnt = CHUNK;
    for (int i = tid; i < cnt; i += 256) atomicAdd(&sm[((u32)dst[e0 + i]) >> 7], 1);
    __syncthreads();
    for (int b = tid; b < NB; b += 256) {
      int c = sm[b];
      if (c) atomicAdd(&bcnt[(size_t)r * NB + b], c);
    }
  }
}

// exclusive scan of NB counters per relation
__global__ __launch_bounds__(1024) void bscan_k(const int* __restrict__ bcnt, int* __restrict__ bptr,
                                                int* __restrict__ bcur) {
  int r = blockIdx.x, t = threadIdx.x;
  const int* c = bcnt + (size_t)r * NB;
  int* p = bptr + (size_t)r * (NB + 1);
  int* cur = bcur + (size_t)r * NB;
  int v = (t < NB) ? c[t] : 0;
  __shared__ int ss[1024];
  ss[t] = v; __syncthreads();
  for (int off = 1; off < 1024; off <<= 1) {
    int u = (t >= off) ? ss[t - off] : 0;
    __syncthreads();
    ss[t] += u;
    __syncthreads();
  }
  if (t < NB) { int e = ss[t] - v; p[t] = e; cur[t] = e; }
  if (t == 1023) p[NB] = ss[1023];
}

// block-local radix partition (coalesced run-writes)
__global__ __launch_bounds__(256) void bscatter_k(const int* __restrict__ src0, const int* __restrict__ dst0,
                                                  const int* __restrict__ src1, const int* __restrict__ dst1,
                                                  const int* __restrict__ src2, const int* __restrict__ dst2,
                                                  int* __restrict__ bcur, u32* __restrict__ recs) {
  int r = blockIdx.y;
  const int* src = (r == 0) ? src0 : (r == 1) ? src1 : src2;
  const int* dst = (r == 0) ? dst0 : (r == 1) ? dst1 : dst2;
  __shared__ int hist[NB];
  __shared__ int lstart[NB];
  __shared__ int lcur[NB];
  __shared__ int badj[NB];
  __shared__ u32 rbuf[CHUNK];
  __shared__ u16 kbuf[CHUNK];
  __shared__ int ss[256];
  int tid = threadIdx.x;
  int e0 = blockIdx.x * CHUNK;
  int cnt = NE - e0; if (cnt > CHUNK) cnt = CHUNK;

  for (int i = tid; i < NB; i += 256) hist[i] = 0;
  __syncthreads();
  for (int i = tid; i < cnt; i += 256) atomicAdd(&hist[((u32)dst[e0 + i]) >> 7], 1);
  __syncthreads();
  int loc[4]; int s = 0;
  int base4 = tid * 4;
#pragma unroll
  for (int j = 0; j < 4; ++j) {
    int idx = base4 + j;
    int v = (idx < NB) ? hist[idx] : 0;
    loc[j] = s; s += v;
  }
  ss[tid] = s; __syncthreads();
  for (int off = 1; off < 256; off <<= 1) {
    int u = (tid >= off) ? ss[tid - off] : 0;
    __syncthreads();
    ss[tid] += u;
    __syncthreads();
  }
  int ex = ss[tid] - s;
#pragma unroll
  for (int j = 0; j < 4; ++j) {
    int idx = base4 + j;
    if (idx < NB) { int e = ex + loc[j]; lstart[idx] = e; lcur[idx] = e; }
  }
  __syncthreads();
  for (int b = tid; b < NB; b += 256) {
    int c = hist[b];
    int g = 0;
    if (c) g = atomicAdd(&bcur[(size_t)r * NB + b], c);
    badj[b] = g - lstart[b];
  }
  __syncthreads();
  for (int i = tid; i < cnt; i += 256) {
    int dN = dst[e0 + i], sN = src[e0 + i];
    int b = ((u32)dN) >> 7;
    int pos = atomicAdd(&lcur[b], 1);
    rbuf[pos] = ((u32)(dN & 127) << 17) | (u32)sN;
    kbuf[pos] = (u16)b;
  }
  __syncthreads();
  u32* out = recs + (size_t)r * NE;
  for (int i = tid; i < cnt; i += 256) {
    int b = kbuf[i];
    out[badj[b] + i] = rbuf[i];
  }
}

// sortgemm: GEMM blocks first (long blocks early), then sort blocks.
// Sort path additionally computes normalized softmax edge weights walpha[e].
__global__ __launch_bounds__(256) void sortgemm_k(u32* __restrict__ recs, const int* __restrict__ bptr,
                                                  int* __restrict__ rowptr,
                                                  const u16* __restrict__ feat_net, const u16* __restrict__ feat_cell,
                                                  const u16* __restrict__ Wl_bf, const u16* __restrict__ Wg_bf,
                                                  u16* __restrict__ P_net, u16* __restrict__ P_cell,
                                                  u16* __restrict__ h0, u16* __restrict__ h1, u16* __restrict__ h2,
                                                  const float* __restrict__ logit, float* __restrict__ walpha) {
  __shared__ u32 smem[128 * SP / 2];   // 34816 B, shared by both paths
  int bid = blockIdx.x, tid = threadIdx.x;
  if (bid < 2 * GB) {
    int ntype = bid >= GB;
    int blk = ntype ? bid - GB : bid;
    u16* lds = (u16*)smem;
    const u16* A = ntype ? feat_cell : feat_net;
    const int row0 = blk * 64;
    const int lane = tid & 63, wv = tid >> 6;
    const int m16 = lane & 15, quad = lane >> 4;
    int arow = row0 + wv * 16 + m16;
    if (arow >= NN) arow = NN - 1;
    const u16* Ab = A + (size_t)arow * 128 + quad * 8;
    bf16x8 a[4];
#pragma unroll
    for (int kk = 0; kk < 4; ++kk) a[kk] = *(const bf16x8*)(Ab + kk * 32);
    if (!ntype) {
      gemm_w(Wl_bf,          256, P_net, lds, tid, row0, a, m16, quad, wv);
      __syncthreads();
      gemm_w(Wg_bf + 16384,  128, h1,    lds, tid, row0, a, m16, quad, wv);
      __syncthreads();
      gemm_w(Wg_bf + 32768,  128, h2,    lds, tid, row0, a, m16, quad, wv);
    } else {
      gemm_w(Wl_bf,          256, P_cell, lds, tid, row0, a, m16, quad, wv);
      __syncthreads();
      gemm_w(Wg_bf,          128, h0,     lds, tid, row0, a, m16, quad, wv);
    }
  } else {
    int sb = bid - 2 * GB;
    int r = sb / NB, b = sb % NB;
    const int* p = bptr + (size_t)r * (NB + 1);
    u32* rec = recs + (size_t)r * NE;
    float* wal = walpha + (size_t)r * NE;
    int* rp = rowptr + (size_t)r * (NN + 1);
    const float* el = logit + (size_t)(2 * r) * NN;
    const float* er = logit + (size_t)(2 * r + 1) * NN;
    int base = p[b], end = p[b + 1];
    int cnt = end - base; if (cnt > BCAP) cnt = BCAP;
    u32* rs = smem;                              // [BCAP] u32
    float* xs = (float*)(smem + BCAP);           // [BCAP] f32
    int* hist = (int*)(smem + 2 * BCAP);         // [128]
    int* excl = hist + 128;                      // [128]
    int* cur  = excl + 128;                      // [128]
    float* den = (float*)(cur + 128);            // [128] sum -> inverse
    float* ers = den + 128;                      // [128] er cache
    for (int i = tid; i < cnt; i += 256) rs[i] = rec[base + i];
    if (tid < 128) {
      hist[tid] = 0;
      den[tid] = 0.f;
      int node = b * 128 + tid;
      ers[tid] = (node < NN) ? er[node] : 0.f;
    }
    __syncthreads();
    for (int i = tid; i < cnt; i += 256) {
      u32 v = rs[i];
      int d = v >> 17;
      float l = el[v & 0x1FFFFu] + ers[d];
      l = (l >= 0.f) ? l : 0.2f * l;
      float x = __expf(l);
      xs[i] = x;
      atomicAdd(&den[d], x);
      atomicAdd(&hist[d], 1);
    }
    __syncthreads();
    if (tid < 128) cur[tid] = hist[tid];
    __syncthreads();
    for (int off = 1; off < 128; off <<= 1) {
      int v = 0;
      if (tid < 128 && tid >= off) v = cur[tid - off];
      __syncthreads();
      if (tid < 128) cur[tid] += v;
      __syncthreads();
    }
    if (tid < 128) {
      int e = cur[tid] - hist[tid];
      excl[tid] = e;
      int node = b * 128 + tid;
      if (node < NN) rp[node] = base + e;
      float dd = den[tid];
      den[tid] = (dd > 0.f) ? 1.f / dd : 0.f;    // -> inverse
    }
    if (b == NB - 1 && tid == 0) rp[NN] = p[NB];
    if (tid < 128) cur[tid] = excl[tid];
    __syncthreads();
    for (int i = tid; i < cnt; i += 256) {
      u32 v = rs[i];
      int d = v >> 17;
      int pos = atomicAdd(&cur[d], 1);
      rec[base + pos] = v & 0x1FFFFu;            // src only, node-sorted
      wal[base + pos] = xs[i] * den[d];          // normalized alpha
    }
  }
}

// tail: whole post-GEMM pipeline, one 256-thread block per 16 nodes.
// net (bid<AB):  {gat0,gat2} dual -> A=gat0 -> F -> F -> A+=gat2 -> F(final fp32)
// cell:          A=relu(P+c) -> A+=gat1 -> F -> F(final fp32)
__global__ __launch_bounds__(256) void tail_k(const u16* __restrict__ h0, const u16* __restrict__ h1,
                                              const u16* __restrict__ h2,
                                              const u32* __restrict__ recs, const float* __restrict__ walpha,
                                              const int* __restrict__ rowptr,
                                              const u16* __restrict__ P_net, const u16* __restrict__ P_cell,
                                              const u16* __restrict__ W2, const float* __restrict__ cvec,
                                              float* __restrict__ out_net, float* __restrict__ out_cell) {
  __shared__ u16 Wlds[128 * SP];
  __shared__ u16 Alds[16 * SP];
  int bid = blockIdx.x, tid = threadIdx.x;
  stageW2(W2, Wlds, tid);
  int sub = tid & 15, g = tid >> 4;
  if (bid < AB) {
    int nb = bid;  // net tile
    int n = nb * 16 + g;
    float accA[8], accB[8];
    gat_dual(n, sub, h0, recs, walpha, rowptr,
             h2, recs + (size_t)2 * NE, walpha + (size_t)2 * NE, rowptr + 2 * (NN + 1),
             accA, accB);
    short8 rb;
#pragma unroll
    for (int t = 0; t < 8; ++t) rb[t] = (short)f2b(accA[t]);
    *(short8*)(&Alds[g * SP + sub * 8]) = rb;
    __syncthreads();                                   // covers W2 staging too
    F_phase<0>(nb, tid, P_net, cvec, Wlds, Alds, nullptr);   // buf_net0 -> Alds
    F_phase<0>(nb, tid, P_net, cvec, Wlds, Alds, nullptr);   // buf_net1 -> Alds
    {  // add precomputed gat2 sum to own slot (same-thread RMW, barriers around)
      short8 pv = *(const short8*)(&Alds[g * SP + sub * 8]);
      short8 nv;
#pragma unroll
      for (int t = 0; t < 8; ++t) nv[t] = (short)f2b(b2f((u16)pv[t]) + accB[t]);
      *(short8*)(&Alds[g * SP + sub * 8]) = nv;
    }
    __syncthreads();
    F_phase<1>(nb, tid, P_net, cvec, Wlds, Alds, (void*)out_net);   // final
  } else {
    int nb = bid - AB;  // cell tile
    {  // elem init: relu(P_cell + cvec) -> Alds (same-thread slot as gat)
      int n = nb * 16 + g;
      short8 pv = *(const short8*)(P_cell + (size_t)n * 128 + sub * 8);
      short8 rb;
#pragma unroll
      for (int t = 0; t < 8; ++t)
        rb[t] = (short)f2b(fmaxf(b2f((u16)pv[t]) + cvec[sub * 8 + t], 0.f));
      *(short8*)(&Alds[g * SP + sub * 8]) = rb;
    }
    // no barrier needed: gat_phase<1> reads the slot this same thread just wrote
    gat_phase<1>(nb, tid, h1, recs + (size_t)NE, walpha + (size_t)NE,
                 rowptr + (NN + 1), Alds);
    __syncthreads();                                   // covers W2 staging too
    F_phase<0>(nb, tid, P_cell, cvec, Wlds, Alds, nullptr);  // buf_cell1 -> Alds
    F_phase<1>(nb, tid, P_cell, cvec, Wlds, Alds, (void*)out_cell);  // final
  }
}

extern "C" void kernel_launch(void* const* d_in, const int* in_sizes, int n_in,
                              void* d_out, int out_size, void* d_ws, size_t ws_size,
                              hipStream_t stream) {
  const float* x_net   = (const float*)d_in[0];
  const float* x_cell  = (const float*)d_in[1];
  const float* Wp_net  = (const float*)d_in[2];
  const float* Wp_cell = (const float*)d_in[3];
  const float* Wg[3] = {(const float*)d_in[4], (const float*)d_in[7], (const float*)d_in[10]};
  const float* al[3] = {(const float*)d_in[5], (const float*)d_in[8], (const float*)d_in[11]};
  const float* ar[3] = {(const float*)d_in[6], (const float*)d_in[9], (const float*)d_in[12]};
  const float* Wl    = (const float*)d_in[13];
  const float* bias  = (const float*)d_in[14];
  const int* src[3] = {(const int*)d_in[15], (const int*)d_in[17], (const int*)d_in[19]};
  const int* dst[3] = {(const int*)d_in[16], (const int*)d_in[18], (const int*)d_in[20]};

  char* ws = (char*)d_ws;
  size_t off = 0;
  auto alloc = [&](size_t b) { void* p = ws + off; off = (off + b + 255) & ~(size_t)255; return p; };
  u16*  feat_net  = (u16*)alloc((size_t)NN * 128 * 2);
  u16*  feat_cell = (u16*)alloc((size_t)NN * 128 * 2);
  u16*  hbuf0     = (u16*)alloc((size_t)NN * 128 * 2);
  u16*  hbuf1     = (u16*)alloc((size_t)NN * 128 * 2);
  u16*  hbuf2     = (u16*)alloc((size_t)NN * 128 * 2);
  u16*  P_net     = (u16*)alloc((size_t)NN * 128 * 2);
  u16*  P_cell    = (u16*)alloc((size_t)NN * 128 * 2);
  float* vecs     = (float*)alloc(7 * 128 * 4);
  float* logit    = (float*)alloc((size_t)6 * NN * 4);
  u16*   Wl_bf    = (u16*)alloc((size_t)128 * 256 * 2);
  u16*   Wg_bf    = (u16*)alloc((size_t)3 * 128 * 128 * 2);
  int*   bcnt     = (int*)alloc((size_t)3 * NB * 4);
  int*   bcur     = (int*)alloc((size_t)3 * NB * 4);
  int*   bptr     = (int*)alloc((size_t)3 * (NB + 1) * 4);
  int*   rowptr   = (int*)alloc((size_t)3 * (NN + 1) * 4);
  u32*   recs     = (u32*)alloc((size_t)3 * NE * 4);
  float* walpha   = (float*)alloc((size_t)3 * NE * 4);

  float* out_f = (float*)d_out;  // [2,N,D] fp32: net then cell
  const u16* W2 = Wl_bf + 128;   // Wl cols 128..255 (ldw 256)
  const float* cvec = vecs + 6 * 128;

  // 1. prep: proj | conv | vec | zero bcnt
  prep_k<<<2 * AB + 138, 256, 0, stream>>>(x_net, x_cell, Wp_net, Wp_cell, feat_net, feat_cell,
                                           Wl, Wg[0], Wg[1], Wg[2], Wl_bf, Wg_bf,
                                           al[0], ar[0], al[1], ar[1], al[2], ar[2], bias, vecs, bcnt);
  // 2. logits | bhist
  logbh_k<<<782 + 3 * NCH, 256, 0, stream>>>(feat_net, feat_cell, vecs, logit,
                                             dst[0], dst[1], dst[2], bcnt);
  // 3. scan
  bscan_k<<<3, 1024, 0, stream>>>(bcnt, bptr, bcur);
  // 4. scatter
  bscatter_k<<<dim3(NCH, 3), 256, 0, stream>>>(src[0], dst[0], src[1], dst[1], src[2], dst[2],
                                               bcur, recs);
  // 5. GEMMs | sort (+ edge-weight precompute)
  sortgemm_k<<<2 * GB + 3 * NB, 256, 0, stream>>>(recs, bptr, rowptr, feat_net, feat_cell,
                                                  Wl_bf, Wg_bf, P_net, P_cell, hbuf0, hbuf1, hbuf2,
                                                  logit, walpha);
  // 6. tail: full node-local pipeline (dual-gather net path)
  tail_k<<<2 * AB, 256, 0, stream>>>(hbuf0, hbuf1, hbuf2, recs, walpha, rowptr,
                                     P_net, P_cell, W2, cvec,
                                     out_f, out_f + (size_t)NN * 128);
}

// Round 13
// 422.808 us; speedup vs baseline: 1.0907x; 1.0907x over previous
//
#include <hip/hip_runtime.h>
#include <hip/hip_bf16.h>
#include <stdint.h>

// ParaGraph: 2 node types (net/cell, N=100000), 3 relations (E=600000 each), D=128.
// I/O FP32. All intermediates bf16. W pre-converted bf16. 6 dispatches:
// prep | logbh | bscan | bscatter | sortgemm | tail.
// sortgemm's sort path also PRECOMPUTES normalized softmax edge weights (walpha):
// el-gather + exp + per-node denominator in LDS, overlapped with GEMM blocks.
// tail_k gather is then pure loads+fma: no shuffles, no exp, no reduction.
#define NN 100000
#define NE 600000
#define SP 136        // LDS row stride (ushorts): 128 + 8 pad
#define NB 782        // ceil(NN/128) dst buckets of 128 nodes
#define BCAP 1600     // LDS rec capacity per bucket (mean 767, sd ~28)
#define CHUNK 4096    // edges per partition block
#define NCH 147       // ceil(NE/CHUNK)
#define GB 1563       // ceil(NN/64) GEMM row-blocks
#define AB 6250       // NN/16 node-tile blocks (exact)

typedef unsigned short u16;
typedef unsigned int u32;
typedef __attribute__((ext_vector_type(8))) short short8;
typedef __attribute__((ext_vector_type(8))) __bf16 bf16x8;
typedef __attribute__((ext_vector_type(4))) float floatx4;

__device__ __forceinline__ float b2f(u16 u) {
  union { float f; u32 i; } c; c.i = ((u32)u) << 16; return c.f;
}
__device__ __forceinline__ u16 f2b(float f) {
  union { float f; u32 i; } c; c.f = f;
  u32 r = c.i + 0x7FFFu + ((c.i >> 16) & 1u);  // RNE
  return (u16)(r >> 16);
}

// ================= device bodies =================

// one W-tile pass (64-row GEMM): stage W -> sync -> MFMA -> store C
__device__ __forceinline__ void gemm_w(const u16* __restrict__ W, int ldw, u16* __restrict__ C,
                                       u16* lds, int tid, int row0, const bf16x8* a,
                                       int m16, int quad, int wv) {
#pragma unroll
  for (int it = 0; it < 8; ++it) {
    int idx = it * 256 + tid;
    int r = idx >> 4, c = (idx & 15) << 3;
    *(short8*)(&lds[r * SP + c]) = *(const short8*)(W + (size_t)r * ldw + c);
  }
  __syncthreads();
  const u16* brow = &lds[m16 * SP + quad * 8];
  floatx4 acc[8];
#pragma unroll
  for (int c = 0; c < 8; ++c) acc[c] = floatx4{0.f, 0.f, 0.f, 0.f};
#pragma unroll
  for (int kk = 0; kk < 4; ++kk) {
#pragma unroll
    for (int c = 0; c < 8; ++c) {
      bf16x8 bfr = *(const bf16x8*)(brow + c * 16 * SP + kk * 32);
      acc[c] = __builtin_amdgcn_mfma_f32_16x16x32_bf16(a[kk], bfr, acc[c], 0, 0, 0);
    }
  }
#pragma unroll
  for (int c = 0; c < 8; ++c) {
    int col = c * 16 + m16;
#pragma unroll
    for (int r = 0; r < 4; ++r) {
      int grow = row0 + wv * 16 + quad * 4 + r;
      if (grow < NN) C[(size_t)grow * 128 + col] = f2b(acc[c][r]);
    }
  }
}

// stage W2 (Wl cols 128..255, ldw 256) into LDS -- plain 16B copies (256 threads)
__device__ __forceinline__ void stageW2(const u16* __restrict__ W2, u16* Wlds, int tid) {
#pragma unroll
  for (int it = 0; it < 8; ++it) {
    int idx = it * 256 + tid;
    int r = idx >> 4, c = (idx & 15) << 3;
    *(short8*)(&Wlds[r * SP + c]) = *(const short8*)(W2 + (size_t)r * 256 + c);
  }
}

// gather phase: group g (16 lanes) accumulates node n's pre-normalized edges into
// Alds row g. Per edge: 2 uniform 4B loads + one 16B h-row load + fma. No shuffles.
template<int INIT>
__device__ __forceinline__ void gat_phase(int nb, int tid, const u16* __restrict__ h,
                                          const u32* __restrict__ srecs,
                                          const float* __restrict__ walpha,
                                          const int* __restrict__ rp, u16* Alds) {
  int sub = tid & 15, g = tid >> 4;
  int n = nb * 16 + g;                    // NN = 6250*16, no tail
  int start = rp[n], end = rp[n + 1];
  float row[8];
  if (INIT) {
    short8 pv = *(const short8*)(&Alds[g * SP + sub * 8]);
#pragma unroll
    for (int t = 0; t < 8; ++t) row[t] = b2f((u16)pv[t]);
  } else {
#pragma unroll
    for (int t = 0; t < 8; ++t) row[t] = 0.f;
  }
  if (start < end) {
    float acc[8];
#pragma unroll
    for (int t = 0; t < 8; ++t) acc[t] = 0.f;
    const u16* hsub = h + sub * 8;
    int e = start;
    for (; e + 4 <= end; e += 4) {
      int s0 = (int)srecs[e],     s1 = (int)srecs[e + 1];
      int s2 = (int)srecs[e + 2], s3 = (int)srecs[e + 3];
      float x0 = walpha[e],     x1 = walpha[e + 1];
      float x2 = walpha[e + 2], x3 = walpha[e + 3];
      short8 h0 = *(const short8*)(hsub + (size_t)s0 * 128);
      short8 h1 = *(const short8*)(hsub + (size_t)s1 * 128);
      short8 h2 = *(const short8*)(hsub + (size_t)s2 * 128);
      short8 h3 = *(const short8*)(hsub + (size_t)s3 * 128);
#pragma unroll
      for (int t = 0; t < 8; ++t) {
        acc[t] += x0 * b2f((u16)h0[t]) + x1 * b2f((u16)h1[t])
                + x2 * b2f((u16)h2[t]) + x3 * b2f((u16)h3[t]);
      }
    }
    for (; e < end; ++e) {
      int sv = (int)srecs[e];
      float x = walpha[e];
      short8 hv = *(const short8*)(hsub + (size_t)sv * 128);
#pragma unroll
      for (int t = 0; t < 8; ++t) acc[t] += x * b2f((u16)hv[t]);
    }
#pragma unroll
    for (int t = 0; t < 8; ++t) row[t] += acc[t];
  }
  short8 rb;
#pragma unroll
  for (int t = 0; t < 8; ++t) rb[t] = (short)f2b(row[t]);
  *(short8*)(&Alds[g * SP + sub * 8]) = rb;
}

// F phase (256 threads, 16 rows): tile = relu(P + Alds @ W2.T + c).
// TO_GLOBAL: fp32 out; else bf16 -> Alds.
template<int TO_GLOBAL>
__device__ __forceinline__ void F_phase(int nb, int tid, const u16* __restrict__ P,
                                        const float* __restrict__ cvec,
                                        const u16* Wlds, u16* Alds, void* __restrict__ out) {
  const int lane = tid & 63, wv = tid >> 6;
  const int m16 = lane & 15, quad = lane >> 4;
  const u16* arow = &Alds[m16 * SP + quad * 8];
  bf16x8 a[4];
#pragma unroll
  for (int kk = 0; kk < 4; ++kk) a[kk] = *(const bf16x8*)(arow + kk * 32);
  if (!TO_GLOBAL) __syncthreads();      // all A reads landed before overwrite
  const u16* brow = &Wlds[m16 * SP + quad * 8];
  floatx4 acc2[2];
#pragma unroll
  for (int cc = 0; cc < 2; ++cc) acc2[cc] = floatx4{0.f, 0.f, 0.f, 0.f};
#pragma unroll
  for (int kk = 0; kk < 4; ++kk) {
#pragma unroll
    for (int cc = 0; cc < 2; ++cc) {
      int ct = wv * 2 + cc;
      bf16x8 bfr = *(const bf16x8*)(brow + ct * 16 * SP + kk * 32);
      acc2[cc] = __builtin_amdgcn_mfma_f32_16x16x32_bf16(a[kk], bfr, acc2[cc], 0, 0, 0);
    }
  }
#pragma unroll
  for (int cc = 0; cc < 2; ++cc) {
    int ct = wv * 2 + cc;
    int col = ct * 16 + m16;
    float cv = cvec[col];
#pragma unroll
    for (int r = 0; r < 4; ++r) {
      int nrow = quad * 4 + r;
      int node = nb * 16 + nrow;
      float v = acc2[cc][r] + b2f(P[(size_t)node * 128 + col]) + cv;
      v = fmaxf(v, 0.f);
      if (TO_GLOBAL) ((float*)out)[(size_t)node * 128 + col] = v;
      else           Alds[nrow * SP + col] = f2b(v);
    }
  }
  if (!TO_GLOBAL) __syncthreads();      // tile complete before next phase reads
}

// ================= kernels =================

// prep: proj (12500) | conv (128) | vec (7) | zero bcnt (3)
__global__ __launch_bounds__(256) void prep_k(const float* __restrict__ x_net, const float* __restrict__ x_cell,
                                              const float* __restrict__ Wp_net, const float* __restrict__ Wp_cell,
                                              u16* __restrict__ feat_net, u16* __restrict__ feat_cell,
                                              const float* __restrict__ Wl, const float* __restrict__ Wg0,
                                              const float* __restrict__ Wg1, const float* __restrict__ Wg2,
                                              u16* __restrict__ Wl_bf, u16* __restrict__ Wg_bf,
                                              const float* al0, const float* ar0, const float* al1,
                                              const float* ar1, const float* al2, const float* ar2,
                                              const float* bias, float* __restrict__ vecs,
                                              int* __restrict__ bcnt) {
  int bid = blockIdx.x, tid = threadIdx.x;
  if (bid < 2 * AB) {
    int y = bid >= AB;
    int bx = y ? bid - AB : bid;
    const float* x  = y ? x_cell : x_net;
    const float* Wp = y ? Wp_cell : Wp_net;
    u16* feat       = y ? feat_cell : feat_net;
    __shared__ float Ws[128 * 17];
    __shared__ float xs[16][17];
#pragma unroll
    for (int it = 0; it < 8; ++it) {
      int idx = it * 256 + tid;
      int j = idx >> 4, k = idx & 15;
      Ws[j * 17 + k] = Wp[idx];
    }
    int n0 = bx * 16;
    { int nn = tid >> 4, k = tid & 15;
      xs[nn][k] = x[(size_t)(n0 + nn) * 16 + k]; }
    __syncthreads();
    int j = tid & 127, g = tid >> 7;
    float acc[8];
#pragma unroll
    for (int r = 0; r < 8; ++r) acc[r] = 0.f;
#pragma unroll
    for (int k = 0; k < 16; ++k) {
      float w = Ws[j * 17 + k];
#pragma unroll
      for (int r = 0; r < 8; ++r) acc[r] += xs[g * 8 + r][k] * w;
    }
#pragma unroll
    for (int r = 0; r < 8; ++r)
      feat[(size_t)(n0 + g * 8 + r) * 128 + j] = f2b(acc[r]);
  } else if (bid < 2 * AB + 128) {
    int cid = bid - 2 * AB;
    int y = cid >> 5, bx = cid & 31;
    const float* src = (y == 0) ? Wl : (y == 1) ? Wg0 : (y == 2) ? Wg1 : Wg2;
    u16* dst = (y == 0) ? Wl_bf : Wg_bf + (size_t)(y - 1) * 16384;
    int n = (y == 0) ? 32768 : 16384;
    int i = (bx * 256 + tid) * 4;
    if (i >= n) return;
    float4 v = *(const float4*)(src + i);
    ushort4 p; p.x = f2b(v.x); p.y = f2b(v.y); p.z = f2b(v.z); p.w = f2b(v.w);
    *(ushort4*)(dst + i) = p;
  } else if (bid < 2 * AB + 135) {
    int a = bid - (2 * AB + 128);
    if (tid >= 128) return;
    int j = tid;
    float s = 0.f;
    if (a < 6) {
      const float* W = (a < 2) ? Wg0 : (a < 4) ? Wg1 : Wg2;
      const float* v = (a == 0) ? al0 : (a == 1) ? ar0 : (a == 2) ? al1 : (a == 3) ? ar1 : (a == 4) ? al2 : ar2;
      for (int i = 0; i < 128; ++i) s += W[i * 128 + j] * v[i];
    } else {
      for (int i = 0; i < 128; ++i) s += Wl[(size_t)j * 256 + 128 + i] * bias[i];
    }
    vecs[a * 128 + j] = s;
  } else {
    int r = bid - (2 * AB + 135);
    for (int i = tid; i < NB; i += 256) bcnt[(size_t)r * NB + i] = 0;
  }
}

// logbh: logits (782) | bhist (441)
__global__ __launch_bounds__(256) void logbh_k(const u16* __restrict__ feat_net, const u16* __restrict__ feat_cell,
                                               const float* __restrict__ vecs, float* __restrict__ outs,
                                               const int* __restrict__ dst0, const int* __restrict__ dst1,
                                               const int* __restrict__ dst2, int* __restrict__ bcnt) {
  __shared__ int sm[NB];
  int bid = blockIdx.x, tid = threadIdx.x;
  if (bid < 782) {
    float* vs = (float*)sm;
#pragma unroll
    for (int it = 0; it < 3; ++it) vs[it * 256 + tid] = vecs[it * 256 + tid];
    __syncthreads();
    int y = bid >= 391;
    int bx = y ? bid - 391 : bid;
    const u16* f = y ? feat_cell : feat_net;
    int n = bx * 256 + tid;
    if (n >= NN) return;
    const u16* row = f + (size_t)n * 128;
    if (y == 0) {
      float s1 = 0.f, s2 = 0.f, s4 = 0.f, s5 = 0.f;
#pragma unroll
      for (int k = 0; k < 128; k += 8) {
        short8 u = *(const short8*)(row + k);
#pragma unroll
        for (int t = 0; t < 8; ++t) {
          float fv = b2f((u16)u[t]);
          s1 += fv * vs[1 * 128 + k + t]; s2 += fv * vs[2 * 128 + k + t];
          s4 += fv * vs[4 * 128 + k + t]; s5 += fv * vs[5 * 128 + k + t];
        }
      }
      outs[(size_t)1 * NN + n] = s1; outs[(size_t)2 * NN + n] = s2;
      outs[(size_t)4 * NN + n] = s4; outs[(size_t)5 * NN + n] = s5;
    } else {
      float s0 = 0.f, s3 = 0.f;
#pragma unroll
      for (int k = 0; k < 128; k += 8) {
        short8 u = *(const short8*)(row + k);
#pragma unroll
        for (int t = 0; t < 8; ++t) {
          float fv = b2f((u16)u[t]);
          s0 += fv * vs[0 * 128 + k + t]; s3 += fv * vs[3 * 128 + k + t];
        }
      }
      outs[(size_t)0 * NN + n] = s0; outs[(size_t)3 * NN + n] = s3;
    }
  } else {
    int e = bid - 782;
    int r = e / NCH, bx = e % NCH;
    const int* dst = (r == 0) ? dst0 : (r == 1) ? dst1 : dst2;
    for (int i = tid; i < NB; i += 256) sm[i] = 0;
    __syncthreads();
    int e0 = bx * CHUNK;
    int cnt = NE - e0; if (cnt > CHUNK) cnt = CHUNK;
    for (int i = tid; i < cnt; i += 256) atomicAdd(&sm[((u32)dst[e0 + i]) >> 7], 1);
    __syncthreads();
    for (int b = tid; b < NB; b += 256) {
      int c = sm[b];
      if (c) atomicAdd(&bcnt[(size_t)r * NB + b], c);
    }
  }
}

// exclusive scan of NB counters per relation
__global__ __launch_bounds__(1024) void bscan_k(const int* __restrict__ bcnt, int* __restrict__ bptr,
                                                int* __restrict__ bcur) {
  int r = blockIdx.x, t = threadIdx.x;
  const int* c = bcnt + (size_t)r * NB;
  int* p = bptr + (size_t)r * (NB + 1);
  int* cur = bcur + (size_t)r * NB;
  int v = (t < NB) ? c[t] : 0;
  __shared__ int ss[1024];
  ss[t] = v; __syncthreads();
  for (int off = 1; off < 1024; off <<= 1) {
    int u = (t >= off) ? ss[t - off] : 0;
    __syncthreads();
    ss[t] += u;
    __syncthreads();
  }
  if (t < NB) { int e = ss[t] - v; p[t] = e; cur[t] = e; }
  if (t == 1023) p[NB] = ss[1023];
}

// block-local radix partition (coalesced run-writes)
__global__ __launch_bounds__(256) void bscatter_k(const int* __restrict__ src0, const int* __restrict__ dst0,
                                                  const int* __restrict__ src1, const int* __restrict__ dst1,
                                                  const int* __restrict__ src2, const int* __restrict__ dst2,
                                                  int* __restrict__ bcur, u32* __restrict__ recs) {
  int r = blockIdx.y;
  const int* src = (r == 0) ? src0 : (r == 1) ? src1 : src2;
  const int* dst = (r == 0) ? dst0 : (r == 1) ? dst1 : dst2;
  __shared__ int hist[NB];
  __shared__ int lstart[NB];
  __shared__ int lcur[NB];
  __shared__ int badj[NB];
  __shared__ u32 rbuf[CHUNK];
  __shared__ u16 kbuf[CHUNK];
  __shared__ int ss[256];
  int tid = threadIdx.x;
  int e0 = blockIdx.x * CHUNK;
  int cnt = NE - e0; if (cnt > CHUNK) cnt = CHUNK;

  for (int i = tid; i < NB; i += 256) hist[i] = 0;
  __syncthreads();
  for (int i = tid; i < cnt; i += 256) atomicAdd(&hist[((u32)dst[e0 + i]) >> 7], 1);
  __syncthreads();
  int loc[4]; int s = 0;
  int base4 = tid * 4;
#pragma unroll
  for (int j = 0; j < 4; ++j) {
    int idx = base4 + j;
    int v = (idx < NB) ? hist[idx] : 0;
    loc[j] = s; s += v;
  }
  ss[tid] = s; __syncthreads();
  for (int off = 1; off < 256; off <<= 1) {
    int u = (tid >= off) ? ss[tid - off] : 0;
    __syncthreads();
    ss[tid] += u;
    __syncthreads();
  }
  int ex = ss[tid] - s;
#pragma unroll
  for (int j = 0; j < 4; ++j) {
    int idx = base4 + j;
    if (idx < NB) { int e = ex + loc[j]; lstart[idx] = e; lcur[idx] = e; }
  }
  __syncthreads();
  for (int b = tid; b < NB; b += 256) {
    int c = hist[b];
    int g = 0;
    if (c) g = atomicAdd(&bcur[(size_t)r * NB + b], c);
    badj[b] = g - lstart[b];
  }
  __syncthreads();
  for (int i = tid; i < cnt; i += 256) {
    int dN = dst[e0 + i], sN = src[e0 + i];
    int b = ((u32)dN) >> 7;
    int pos = atomicAdd(&lcur[b], 1);
    rbuf[pos] = ((u32)(dN & 127) << 17) | (u32)sN;
    kbuf[pos] = (u16)b;
  }
  __syncthreads();
  u32* out = recs + (size_t)r * NE;
  for (int i = tid; i < cnt; i += 256) {
    int b = kbuf[i];
    out[badj[b] + i] = rbuf[i];
  }
}

// sortgemm: GEMM blocks first (long blocks early), then sort blocks.
// Sort path additionally computes normalized softmax edge weights walpha[e]
// (el gather + exp + per-node LDS-atomic denominator), aligned with sorted recs.
__global__ __launch_bounds__(256) void sortgemm_k(u32* __restrict__ recs, const int* __restrict__ bptr,
                                                  int* __restrict__ rowptr,
                                                  const u16* __restrict__ feat_net, const u16* __restrict__ feat_cell,
                                                  const u16* __restrict__ Wl_bf, const u16* __restrict__ Wg_bf,
                                                  u16* __restrict__ P_net, u16* __restrict__ P_cell,
                                                  u16* __restrict__ h0, u16* __restrict__ h1, u16* __restrict__ h2,
                                                  const float* __restrict__ logit, float* __restrict__ walpha) {
  __shared__ u32 smem[128 * SP / 2];   // 34816 B, shared by both paths
  int bid = blockIdx.x, tid = threadIdx.x;
  if (bid < 2 * GB) {
    int ntype = bid >= GB;
    int blk = ntype ? bid - GB : bid;
    u16* lds = (u16*)smem;
    const u16* A = ntype ? feat_cell : feat_net;
    const int row0 = blk * 64;
    const int lane = tid & 63, wv = tid >> 6;
    const int m16 = lane & 15, quad = lane >> 4;
    int arow = row0 + wv * 16 + m16;
    if (arow >= NN) arow = NN - 1;
    const u16* Ab = A + (size_t)arow * 128 + quad * 8;
    bf16x8 a[4];
#pragma unroll
    for (int kk = 0; kk < 4; ++kk) a[kk] = *(const bf16x8*)(Ab + kk * 32);
    if (!ntype) {
      gemm_w(Wl_bf,          256, P_net, lds, tid, row0, a, m16, quad, wv);
      __syncthreads();
      gemm_w(Wg_bf + 16384,  128, h1,    lds, tid, row0, a, m16, quad, wv);
      __syncthreads();
      gemm_w(Wg_bf + 32768,  128, h2,    lds, tid, row0, a, m16, quad, wv);
    } else {
      gemm_w(Wl_bf,          256, P_cell, lds, tid, row0, a, m16, quad, wv);
      __syncthreads();
      gemm_w(Wg_bf,          128, h0,     lds, tid, row0, a, m16, quad, wv);
    }
  } else {
    int sb = bid - 2 * GB;
    int r = sb / NB, b = sb % NB;
    const int* p = bptr + (size_t)r * (NB + 1);
    u32* rec = recs + (size_t)r * NE;
    float* wal = walpha + (size_t)r * NE;
    int* rp = rowptr + (size_t)r * (NN + 1);
    const float* el = logit + (size_t)(2 * r) * NN;
    const float* er = logit + (size_t)(2 * r + 1) * NN;
    int base = p[b], end = p[b + 1];
    int cnt = end - base; if (cnt > BCAP) cnt = BCAP;
    u32* rs = smem;                              // [BCAP] u32
    float* xs = (float*)(smem + BCAP);           // [BCAP] f32
    int* hist = (int*)(smem + 2 * BCAP);         // [128]
    int* excl = hist + 128;                      // [128]
    int* cur  = excl + 128;                      // [128]
    float* den = (float*)(cur + 128);            // [128] sum -> inverse
    float* ers = den + 128;                      // [128] er cache
    for (int i = tid; i < cnt; i += 256) rs[i] = rec[base + i];
    if (tid < 128) {
      hist[tid] = 0;
      den[tid] = 0.f;
      int node = b * 128 + tid;
      ers[tid] = (node < NN) ? er[node] : 0.f;
    }
    __syncthreads();
    // count + edge-weight + denominator
    for (int i = tid; i < cnt; i += 256) {
      u32 v = rs[i];
      int d = v >> 17;
      float l = el[v & 0x1FFFFu] + ers[d];
      l = (l >= 0.f) ? l : 0.2f * l;
      float x = __expf(l);
      xs[i] = x;
      atomicAdd(&den[d], x);
      atomicAdd(&hist[d], 1);
    }
    __syncthreads();
    if (tid < 128) cur[tid] = hist[tid];
    __syncthreads();
    for (int off = 1; off < 128; off <<= 1) {
      int v = 0;
      if (tid < 128 && tid >= off) v = cur[tid - off];
      __syncthreads();
      if (tid < 128) cur[tid] += v;
      __syncthreads();
    }
    if (tid < 128) {
      int e = cur[tid] - hist[tid];
      excl[tid] = e;
      int node = b * 128 + tid;
      if (node < NN) rp[node] = base + e;
      float dd = den[tid];
      den[tid] = (dd > 0.f) ? 1.f / dd : 0.f;    // -> inverse
    }
    if (b == NB - 1 && tid == 0) rp[NN] = p[NB];
    if (tid < 128) cur[tid] = excl[tid];
    __syncthreads();
    for (int i = tid; i < cnt; i += 256) {
      u32 v = rs[i];
      int d = v >> 17;
      int pos = atomicAdd(&cur[d], 1);
      rec[base + pos] = v & 0x1FFFFu;            // src only, node-sorted
      wal[base + pos] = xs[i] * den[d];          // normalized alpha
    }
  }
}

// tail: whole post-GEMM pipeline, one 256-thread block per 16 nodes.
// net (bid<AB):  A=gat0 -> F -> F -> A+=gat2 -> F(final fp32)
// cell:          A=relu(P+c) -> A+=gat1 -> F -> F(final fp32)
__global__ __launch_bounds__(256) void tail_k(const u16* __restrict__ h0, const u16* __restrict__ h1,
                                              const u16* __restrict__ h2,
                                              const u32* __restrict__ recs, const float* __restrict__ walpha,
                                              const int* __restrict__ rowptr,
                                              const u16* __restrict__ P_net, const u16* __restrict__ P_cell,
                                              const u16* __restrict__ W2, const float* __restrict__ cvec,
                                              float* __restrict__ out_net, float* __restrict__ out_cell) {
  __shared__ u16 Wlds[128 * SP];
  __shared__ u16 Alds[16 * SP];
  int bid = blockIdx.x, tid = threadIdx.x;
  stageW2(W2, Wlds, tid);
  if (bid < AB) {
    int nb = bid;  // net tile
    gat_phase<0>(nb, tid, h0, recs, walpha, rowptr, Alds);
    __syncthreads();                                   // covers W2 staging too
    F_phase<0>(nb, tid, P_net, cvec, Wlds, Alds, nullptr);   // buf_net0 -> Alds
    F_phase<0>(nb, tid, P_net, cvec, Wlds, Alds, nullptr);   // buf_net1 -> Alds
    gat_phase<1>(nb, tid, h2, recs + (size_t)2 * NE, walpha + (size_t)2 * NE,
                 rowptr + 2 * (NN + 1), Alds);
    __syncthreads();
    F_phase<1>(nb, tid, P_net, cvec, Wlds, Alds, (void*)out_net);   // final
  } else {
    int nb = bid - AB;  // cell tile
    {  // elem init: relu(P_cell + cvec) -> Alds (same-thread slot as gat)
      int sub = tid & 15, g = tid >> 4;
      int n = nb * 16 + g;
      short8 pv = *(const short8*)(P_cell + (size_t)n * 128 + sub * 8);
      short8 rb;
#pragma unroll
      for (int t = 0; t < 8; ++t)
        rb[t] = (short)f2b(fmaxf(b2f((u16)pv[t]) + cvec[sub * 8 + t], 0.f));
      *(short8*)(&Alds[g * SP + sub * 8]) = rb;
    }
    // no barrier needed: gat_phase<1> reads the slot this same thread just wrote
    gat_phase<1>(nb, tid, h1, recs + (size_t)NE, walpha + (size_t)NE,
                 rowptr + (NN + 1), Alds);
    __syncthreads();                                   // covers W2 staging too
    F_phase<0>(nb, tid, P_cell, cvec, Wlds, Alds, nullptr);  // buf_cell1 -> Alds
    F_phase<1>(nb, tid, P_cell, cvec, Wlds, Alds, (void*)out_cell);  // final
  }
}

extern "C" void kernel_launch(void* const* d_in, const int* in_sizes, int n_in,
                              void* d_out, int out_size, void* d_ws, size_t ws_size,
                              hipStream_t stream) {
  const float* x_net   = (const float*)d_in[0];
  const float* x_cell  = (const float*)d_in[1];
  const float* Wp_net  = (const float*)d_in[2];
  const float* Wp_cell = (const float*)d_in[3];
  const float* Wg[3] = {(const float*)d_in[4], (const float*)d_in[7], (const float*)d_in[10]};
  const float* al[3] = {(const float*)d_in[5], (const float*)d_in[8], (const float*)d_in[11]};
  const float* ar[3] = {(const float*)d_in[6], (const float*)d_in[9], (const float*)d_in[12]};
  const float* Wl    = (const float*)d_in[13];
  const float* bias  = (const float*)d_in[14];
  const int* src[3] = {(const int*)d_in[15], (const int*)d_in[17], (const int*)d_in[19]};
  const int* dst[3] = {(const int*)d_in[16], (const int*)d_in[18], (const int*)d_in[20]};

  char* ws = (char*)d_ws;
  size_t off = 0;
  auto alloc = [&](size_t b) { void* p = ws + off; off = (off + b + 255) & ~(size_t)255; return p; };
  u16*  feat_net  = (u16*)alloc((size_t)NN * 128 * 2);
  u16*  feat_cell = (u16*)alloc((size_t)NN * 128 * 2);
  u16*  hbuf0     = (u16*)alloc((size_t)NN * 128 * 2);
  u16*  hbuf1     = (u16*)alloc((size_t)NN * 128 * 2);
  u16*  hbuf2     = (u16*)alloc((size_t)NN * 128 * 2);
  u16*  P_net     = (u16*)alloc((size_t)NN * 128 * 2);
  u16*  P_cell    = (u16*)alloc((size_t)NN * 128 * 2);
  float* vecs     = (float*)alloc(7 * 128 * 4);
  float* logit    = (float*)alloc((size_t)6 * NN * 4);
  u16*   Wl_bf    = (u16*)alloc((size_t)128 * 256 * 2);
  u16*   Wg_bf    = (u16*)alloc((size_t)3 * 128 * 128 * 2);
  int*   bcnt     = (int*)alloc((size_t)3 * NB * 4);
  int*   bcur     = (int*)alloc((size_t)3 * NB * 4);
  int*   bptr     = (int*)alloc((size_t)3 * (NB + 1) * 4);
  int*   rowptr   = (int*)alloc((size_t)3 * (NN + 1) * 4);
  u32*   recs     = (u32*)alloc((size_t)3 * NE * 4);
  float* walpha   = (float*)alloc((size_t)3 * NE * 4);

  float* out_f = (float*)d_out;  // [2,N,D] fp32: net then cell
  const u16* W2 = Wl_bf + 128;   // Wl cols 128..255 (ldw 256)
  const float* cvec = vecs + 6 * 128;

  // 1. prep: proj | conv | vec | zero bcnt
  prep_k<<<2 * AB + 138, 256, 0, stream>>>(x_net, x_cell, Wp_net, Wp_cell, feat_net, feat_cell,
                                           Wl, Wg[0], Wg[1], Wg[2], Wl_bf, Wg_bf,
                                           al[0], ar[0], al[1], ar[1], al[2], ar[2], bias, vecs, bcnt);
  // 2. logits | bhist
  logbh_k<<<782 + 3 * NCH, 256, 0, stream>>>(feat_net, feat_cell, vecs, logit,
                                             dst[0], dst[1], dst[2], bcnt);
  // 3. scan
  bscan_k<<<3, 1024, 0, stream>>>(bcnt, bptr, bcur);
  // 4. scatter
  bscatter_k<<<dim3(NCH, 3), 256, 0, stream>>>(src[0], dst[0], src[1], dst[1], src[2], dst[2],
                                               bcur, recs);
  // 5. GEMMs | sort (+ edge-weight precompute)
  sortgemm_k<<<2 * GB + 3 * NB, 256, 0, stream>>>(recs, bptr, rowptr, feat_net, feat_cell,
                                                  Wl_bf, Wg_bf, P_net, P_cell, hbuf0, hbuf1, hbuf2,
                                                  logit, walpha);
  // 6. tail: full node-local pipeline (shuffle-free gather)
  tail_k<<<2 * AB, 256, 0, stream>>>(hbuf0, hbuf1, hbuf2, recs, walpha, rowptr,
                                     P_net, P_cell, W2, cvec,
                                     out_f, out_f + (size_t)NN * 128);
}